// Round 19
// baseline (147.792 us; speedup 1.0000x reference)
//
#include <hip/hip_runtime.h>
#include <cmath>

#define BATCH 32
#define HALF_B 16
#define CCH 512
#define HW 4096
#define KCL 17
#define NSLAB 8

typedef __attribute__((ext_vector_type(8))) short short8;
typedef __attribute__((ext_vector_type(16))) float f32x16;

__device__ __forceinline__ unsigned pack_bf16(float a, float b) {
  unsigned ua = (__float_as_uint(a) + 0x8000u) >> 16;
  unsigned ub = (__float_as_uint(b) + 0x8000u) & 0xFFFF0000u;
  return ua | ub;
}
__device__ __forceinline__ float bf_lo(unsigned u) { return __uint_as_float(u << 16); }
__device__ __forceinline__ float bf_hi(unsigned u) { return __uint_as_float(u & 0xFFFF0000u); }

// ws layout (bytes)
#define WT_OFF 0
#define WT_BYTES (CCH * 20 * 4)                        // 40960
#define PART_OFF WT_BYTES
#define PART_BYTES (BATCH * NSLAB * KCL * HW * 2)      // 35651584 bf16 [b][slab8][17][4096]
#define SIG_OFF (PART_OFF + PART_BYTES)
#define SIG_BYTES ((size_t)BATCH * 32 * HW * 2)        // 8388608  bf16 [b][32pad][4096]
#define WS_NEED (SIG_OFF + SIG_BYTES)                  // ~44 MB

__global__ void transpose_w_kernel(const float* __restrict__ w, float* __restrict__ wT) {
  int c = threadIdx.x;  // 512 threads
  #pragma unroll
  for (int k = 0; k < 20; ++k)
    wT[c * 20 + k] = (k < KCL) ? w[k * CCH + c] : 0.f;
}

// K1 (per half): cam partials, pure-read stream (REGULAR cached loads so the
// x-half stays L3-resident for k3). 256 blocks x 512 thr = 8 waves/CU.
// rowhalf = readfirstlane(t>>8) keeps w loads wave-uniform scalar.
__global__ __launch_bounds__(512)
void k1_campart(const float* __restrict__ x, const float* __restrict__ wT,
                unsigned short* __restrict__ part, int b0) {
  const int blk = blockIdx.x;            // 256 = b16*16 + slab*4 + pxq
  const int b = b0 + (blk >> 4);
  const int slab = (blk >> 2) & 3;
  const int pxq = blk & 3;
  const int t = threadIdx.x;
  const int rowhalf = __builtin_amdgcn_readfirstlane(t >> 8);  // 0/1, wave-uniform
  const int px0 = pxq * 1024 + (t & 255) * 4;
  const float* xp = x + (size_t)(b * CCH + slab * 128 + rowhalf) * HW + px0;

  float cam[KCL][4];
  #pragma unroll
  for (int k = 0; k < KCL; ++k)
    #pragma unroll
    for (int i = 0; i < 4; ++i) cam[k][i] = 0.f;

  #pragma unroll 4
  for (int r = 0; r < 64; ++r) {
    const float4 v = *reinterpret_cast<const float4*>(xp + (size_t)(2 * r) * HW);
    const float* wr = wT + (slab * 128 + 2 * r + rowhalf) * 20;  // scalar
    #pragma unroll
    for (int k = 0; k < KCL; ++k) {
      cam[k][0] = fmaf(wr[k], v.x, cam[k][0]);
      cam[k][1] = fmaf(wr[k], v.y, cam[k][1]);
      cam[k][2] = fmaf(wr[k], v.z, cam[k][2]);
      cam[k][3] = fmaf(wr[k], v.w, cam[k][3]);
    }
  }

  unsigned short* pp = part + ((size_t)(b * NSLAB + slab * 2 + rowhalf) * KCL) * HW + px0;
  #pragma unroll
  for (int k = 0; k < KCL; ++k) {
    uint2 u = make_uint2(pack_bf16(cam[k][0], cam[k][1]), pack_bf16(cam[k][2], cam[k][3]));
    *reinterpret_cast<uint2*>(pp + (size_t)k * HW) = u;
  }
}

// K2 (per half): reduce 8 slabs + bias -> sigmoid (bf16) + exact g store.
__global__ __launch_bounds__(512)
void k2_sig(const unsigned short* __restrict__ part, const float* __restrict__ bias,
            float* __restrict__ out_g, unsigned short* __restrict__ sig, int b0) {
  const int b = b0 + blockIdx.x / KCL;
  const int k = blockIdx.x % KCL;
  const int t = threadIdx.x;
  const float bk = bias[k];
  const int px0 = t * 8;
  const size_t SL = (size_t)KCL * HW;
  const unsigned short* pb = part + ((size_t)b * NSLAB) * SL + (size_t)k * HW + px0;

  unsigned a[NSLAB][4];
  #pragma unroll
  for (int s = 0; s < NSLAB; ++s)
    *reinterpret_cast<uint4*>(a[s]) = *reinterpret_cast<const uint4*>(pb + s * SL);

  float gs = 0.f;
  unsigned so[4];
  #pragma unroll
  for (int j = 0; j < 4; ++j) {
    float c0 = bk, c1 = bk;
    #pragma unroll
    for (int s = 0; s < NSLAB; ++s) {
      c0 += bf_lo(a[s][j]);
      c1 += bf_hi(a[s][j]);
    }
    gs += c0 + c1;
    float s0 = 1.f / (1.f + __expf(-c0));
    float s1 = 1.f / (1.f + __expf(-c1));
    so[j] = pack_bf16(s0, s1);
  }
  *reinterpret_cast<uint4*>(sig + ((size_t)b * 32 + k) * HW + px0) =
      *reinterpret_cast<uint4*>(so);

  const int lane = t & 63, wv = t >> 6;
  #pragma unroll
  for (int o = 1; o < 64; o <<= 1) gs += __shfl_xor(gs, o, 64);
  __shared__ float gr[8];
  if (lane == 0) gr[wv] = gs;
  __syncthreads();
  if (t == 0) {
    float s = gr[0] + gr[1] + gr[2] + gr[3] + gr[4] + gr[5] + gr[6] + gr[7];
    out_g[b * KCL + k] = s * (1.f / 4096.f);
  }
}

// K3 (per half): sf = (1/4096) * x[32ch rows] @ sigT via MFMA. Reads f32 x
// (expected L3-resident from k1), packs bf16 in regs. Barrier-free main loop.
__global__ __launch_bounds__(512, 2)
void k3_sf(const float* __restrict__ x, const unsigned short* __restrict__ sig,
           float* __restrict__ out_sf, int b0) {
  __shared__ float P[8 * 1024];  // 32 KB K-reduce scratch
  // XCD-chunked swizzle over 256 blocks: 32 per XCD -> same-b blocks cluster
  const int p = blockIdx.x;
  const int lid = (p & 7) * 32 + (p >> 3);
  const int b = b0 + (lid >> 4);
  const int chs = lid & 15;
  const int t = threadIdx.x;
  const int lane = t & 63;
  const int wv = __builtin_amdgcn_readfirstlane(t >> 6);  // 0..7, K-split
  const int m = lane & 31;
  const int h = lane >> 5;

  const float* ap = x + ((size_t)(b * CCH + chs * 32 + m)) * HW;
  const unsigned short* bp = sig + ((size_t)(b * 32 + m)) * HW;

  f32x16 acc;
  #pragma unroll
  for (int i = 0; i < 16; ++i) acc[i] = 0.f;

  // wave wv covers px [wv*512, wv*512+512); lane (m,h) walks 32B chunks stride 64B
  const int pbase = wv * 512 + h * 8;
  #pragma unroll 4
  for (int i = 0; i < 32; ++i) {
    const int px = pbase + i * 16;
    const float4 v0 = *reinterpret_cast<const float4*>(ap + px);
    const float4 v1 = *reinterpret_cast<const float4*>(ap + px + 4);
    uint4 au;
    au.x = pack_bf16(v0.x, v0.y);
    au.y = pack_bf16(v0.z, v0.w);
    au.z = pack_bf16(v1.x, v1.y);
    au.w = pack_bf16(v1.z, v1.w);
    const short8 a = *reinterpret_cast<const short8*>(&au);
    const short8 bb = *reinterpret_cast<const short8*>(bp + px);
    acc = __builtin_amdgcn_mfma_f32_32x32x16_bf16(a, bb, acc, 0, 0, 0);
  }

  // K-reduce across 8 waves (validated C-layout map)
  #pragma unroll
  for (int r = 0; r < 16; ++r) {
    const int chr = (r & 3) + 8 * (r >> 2) + 4 * h;
    P[wv * 1024 + m * 32 + chr] = acc[r];  // index = cls*32 + ch
  }
  __syncthreads();
  const float inv = 1.f / 4096.f;
  {
    float s = 0.f;
    #pragma unroll
    for (int w8 = 0; w8 < 8; ++w8) s += P[w8 * 1024 + t];
    const int n = t >> 5, ch = t & 31;  // n = 0..15
    out_sf[((size_t)b * KCL + n) * CCH + chs * 32 + ch] = s * inv;
    if (t < 32) {  // n = 16
      float s2 = 0.f;
      #pragma unroll
      for (int w8 = 0; w8 < 8; ++w8) s2 += P[w8 * 1024 + 512 + t];
      out_sf[((size_t)b * KCL + 16) * CCH + chs * 32 + t] = s2 * inv;
    }
  }
}

extern "C" void kernel_launch(void* const* d_in, const int* in_sizes, int n_in,
                              void* d_out, int out_size, void* d_ws, size_t ws_size,
                              hipStream_t stream) {
  const float* x = (const float*)d_in[0];
  const float* w = (const float*)d_in[1];
  const float* bias = (const float*)d_in[2];
  float* out = (float*)d_out;
  float* outg = out;                 // (32,17)
  float* outsf = out + BATCH * KCL;  // (32,17,512)

  char* ws = (char*)d_ws;
  float* wT = (float*)(ws + WT_OFF);
  unsigned short* part = (unsigned short*)(ws + PART_OFF);
  unsigned short* sig = (unsigned short*)(ws + SIG_OFF);

  transpose_w_kernel<<<1, 512, 0, stream>>>(w, wT);
  for (int half = 0; half < 2; ++half) {
    const int b0 = half * HALF_B;
    k1_campart<<<256, 512, 0, stream>>>(x, wT, part, b0);
    k2_sig<<<HALF_B * KCL, 512, 0, stream>>>(part, bias, outg, sig, b0);
    k3_sf<<<256, 512, 0, stream>>>(x, sig, outsf, b0);
  }
}

// Round 20
// 140.949 us; speedup vs baseline: 1.0486x; 1.0486x over previous
//
#include <hip/hip_runtime.h>
#include <cmath>

#define BATCH 32
#define CCH 512
#define HW 4096
#define KCL 17

typedef __attribute__((ext_vector_type(8))) short short8;
typedef __attribute__((ext_vector_type(16))) float f32x16;
typedef __attribute__((ext_vector_type(4))) float f32x4;
typedef __attribute__((ext_vector_type(2))) unsigned uint2v;

__device__ __forceinline__ unsigned pack_bf16(float a, float b) {
  unsigned ua = (__float_as_uint(a) + 0x8000u) >> 16;
  unsigned ub = (__float_as_uint(b) + 0x8000u) & 0xFFFF0000u;
  return ua | ub;
}
__device__ __forceinline__ f32x4 ntload4(const float* p) {
  return __builtin_nontemporal_load(reinterpret_cast<const f32x4*>(p));
}
__device__ __forceinline__ void ntstore2(unsigned short* p, unsigned a, unsigned b) {
  uint2v v; v.x = a; v.y = b;
  __builtin_nontemporal_store(v, reinterpret_cast<uint2v*>(p));
}

// ws layout (bytes)
#define WT_OFF 0
#define WT_BYTES (CCH * 20 * 4)                    // 40960
#define SIG_OFF WT_BYTES
#define SIG_BYTES ((size_t)BATCH * 32 * HW * 2)    // 8388608   bf16 [b][32pad][4096]
#define XBF_OFF (SIG_OFF + SIG_BYTES)
#define XBF_BYTES ((size_t)BATCH * CCH * HW * 2)   // 134217728 bf16 [b][ch][4096]
#define WS_NEED (XBF_OFF + XBF_BYTES)              // ~143 MB (ws ~1 GB)

// K0: wT fill + zero out_g (g accumulated via atomics in k12)
__global__ void k0_setup(const float* __restrict__ w, float* __restrict__ wT,
                         float* __restrict__ out_g) {
  int c = threadIdx.x;  // 512
  #pragma unroll
  for (int k = 0; k < 20; ++k) wT[c * 20 + k] = (k < KCL) ? w[k * CCH + c] : 0.f;
  if (c < BATCH * KCL) out_g[c] = 0.f;
  if (c < BATCH * KCL - 512) out_g[512 + c] = 0.f;
}

// K12: fused cam+sigmoid+xbf (r17 structure, 118 us proven) with ONE change:
// xbf stores are NONTEMPORAL (bypass L2/L3 allocation) to test whether
// write-allocate pollution is what throttles the read stream to 3.9 TB/s.
__global__ __launch_bounds__(512)
void k12_cam_sig(const float* __restrict__ x, const float* __restrict__ wT,
                 const float* __restrict__ bias, float* __restrict__ out_g,
                 unsigned short* __restrict__ xbf, unsigned short* __restrict__ sig) {
  extern __shared__ float R[];  // [2][17][512] f32 = 69632 B
  const int t = threadIdx.x;
  const int slab = __builtin_amdgcn_readfirstlane(t >> 7);  // 0..3, wave-uniform
  const int pxg = t & 127;
  const int b = blockIdx.x >> 3;
  const int slice = blockIdx.x & 7;
  const int px = slice * 512 + pxg * 4;
  const float* xp = x + ((size_t)(b * CCH + slab * 128)) * HW + px;
  unsigned short* xbp = xbf + ((size_t)(b * CCH + slab * 128)) * HW + px;

  float cam[KCL][4];
  #pragma unroll
  for (int k = 0; k < KCL; ++k)
    #pragma unroll
    for (int i = 0; i < 4; ++i) cam[k][i] = 0.f;

  f32x4 v0[4], v1[4];
  #pragma unroll
  for (int j = 0; j < 4; ++j) v0[j] = ntload4(xp + (size_t)j * HW);

  #pragma unroll 1
  for (int gp = 0; gp < 16; ++gp) {
    const int c0 = gp * 8;
    #pragma unroll
    for (int j = 0; j < 4; ++j) v1[j] = ntload4(xp + (size_t)(c0 + 4 + j) * HW);
    #pragma unroll
    for (int j = 0; j < 4; ++j) {
      const f32x4 v = v0[j];
      const float* wr = wT + (slab * 128 + c0 + j) * 20;  // scalar (slab SGPR)
      #pragma unroll
      for (int k = 0; k < KCL; ++k) {
        cam[k][0] = fmaf(wr[k], v.x, cam[k][0]);
        cam[k][1] = fmaf(wr[k], v.y, cam[k][1]);
        cam[k][2] = fmaf(wr[k], v.z, cam[k][2]);
        cam[k][3] = fmaf(wr[k], v.w, cam[k][3]);
      }
      ntstore2(xbp + (size_t)(c0 + j) * HW, pack_bf16(v.x, v.y), pack_bf16(v.z, v.w));
    }
    if (gp < 15) {
      #pragma unroll
      for (int j = 0; j < 4; ++j) v0[j] = ntload4(xp + (size_t)(c0 + 8 + j) * HW);
    }
    #pragma unroll
    for (int j = 0; j < 4; ++j) {
      const f32x4 v = v1[j];
      const float* wr = wT + (slab * 128 + c0 + 4 + j) * 20;
      #pragma unroll
      for (int k = 0; k < KCL; ++k) {
        cam[k][0] = fmaf(wr[k], v.x, cam[k][0]);
        cam[k][1] = fmaf(wr[k], v.y, cam[k][1]);
        cam[k][2] = fmaf(wr[k], v.z, cam[k][2]);
        cam[k][3] = fmaf(wr[k], v.w, cam[k][3]);
      }
      ntstore2(xbp + (size_t)(c0 + 4 + j) * HW, pack_bf16(v.x, v.y), pack_bf16(v.z, v.w));
    }
  }

  // reduce 4 slab-partials -> slab 0
  if (slab >= 2) {
    float* Rb = R + (slab - 2) * (KCL * 512);
    #pragma unroll
    for (int k = 0; k < KCL; ++k)
      *reinterpret_cast<float4*>(Rb + k * 512 + pxg * 4) =
          make_float4(cam[k][0], cam[k][1], cam[k][2], cam[k][3]);
  }
  __syncthreads();
  if (slab < 2) {
    const float* Rb = R + slab * (KCL * 512);
    #pragma unroll
    for (int k = 0; k < KCL; ++k) {
      const float4 r = *reinterpret_cast<const float4*>(Rb + k * 512 + pxg * 4);
      cam[k][0] += r.x; cam[k][1] += r.y; cam[k][2] += r.z; cam[k][3] += r.w;
    }
  }
  __syncthreads();
  if (slab == 1) {
    #pragma unroll
    for (int k = 0; k < KCL; ++k)
      *reinterpret_cast<float4*>(R + k * 512 + pxg * 4) =
          make_float4(cam[k][0], cam[k][1], cam[k][2], cam[k][3]);
  }
  __syncthreads();
  if (slab == 0) {
    const float inv = 1.f / 4096.f;
    const int lane = t & 63;
    #pragma unroll
    for (int k = 0; k < KCL; ++k) {
      const float4 r = *reinterpret_cast<const float4*>(R + k * 512 + pxg * 4);
      const float bk = bias[k];
      float c0 = cam[k][0] + r.x + bk;
      float c1 = cam[k][1] + r.y + bk;
      float c2 = cam[k][2] + r.z + bk;
      float c3 = cam[k][3] + r.w + bk;
      unsigned u0 = pack_bf16(1.f / (1.f + __expf(-c0)), 1.f / (1.f + __expf(-c1)));
      unsigned u1 = pack_bf16(1.f / (1.f + __expf(-c2)), 1.f / (1.f + __expf(-c3)));
      *reinterpret_cast<uint2*>(sig + ((size_t)(b * 32 + k)) * HW + px) = make_uint2(u0, u1);
      float gk = c0 + c1 + c2 + c3;
      #pragma unroll
      for (int o = 1; o < 64; o <<= 1) gk += __shfl_xor(gk, o, 64);
      if (lane == 0) atomicAdd(out_g + b * KCL + k, gk * inv);
    }
  }
}

// K3: sf[b,:,chs*32..+32] = (1/4096) * xbf[32ch rows] @ sigT. Barrier-free MFMA
// global-gather; xbf now HBM-resident (nt-stored), sig L3-resident.
__global__ __launch_bounds__(512, 2)
void k3_sf(const unsigned short* __restrict__ xbf, const unsigned short* __restrict__ sig,
           float* __restrict__ out_sf) {
  __shared__ float P[8 * 1024];  // 32 KB K-reduce scratch
  // XCD-chunked bijective swizzle: 512 blocks, 64 per XCD -> same-b blocks cluster
  const int p = blockIdx.x;
  const int lid = (p & 7) * 64 + (p >> 3);
  const int b = lid >> 4;
  const int chs = lid & 15;
  const int t = threadIdx.x;
  const int lane = t & 63;
  const int wv = __builtin_amdgcn_readfirstlane(t >> 6);  // 0..7, K-split
  const int m = lane & 31;
  const int h = lane >> 5;

  const unsigned short* ap = xbf + ((size_t)(b * CCH + chs * 32 + m)) * HW;
  const unsigned short* bp = sig + ((size_t)(b * 32 + m)) * HW;

  f32x16 acc;
  #pragma unroll
  for (int i = 0; i < 16; ++i) acc[i] = 0.f;

  // wave wv covers px slots [wv*64, wv*64+64): 2-KB contiguous stream per row
  const int obase = (wv * 64 + h) * 8;
  #pragma unroll 4
  for (int i = 0; i < 32; ++i) {
    const int o = obase + i * 16;  // ushort offset
    const short8 a = *reinterpret_cast<const short8*>(ap + o);
    const short8 bb = *reinterpret_cast<const short8*>(bp + o);
    acc = __builtin_amdgcn_mfma_f32_32x32x16_bf16(a, bb, acc, 0, 0, 0);
  }

  // K-reduce across 8 waves (validated C-layout map)
  #pragma unroll
  for (int r = 0; r < 16; ++r) {
    const int chr = (r & 3) + 8 * (r >> 2) + 4 * h;
    P[wv * 1024 + m * 32 + chr] = acc[r];  // index = cls*32 + ch
  }
  __syncthreads();
  const float inv = 1.f / 4096.f;
  {
    float s = 0.f;
    #pragma unroll
    for (int w8 = 0; w8 < 8; ++w8) s += P[w8 * 1024 + t];
    const int n = t >> 5, ch = t & 31;  // n = 0..15
    out_sf[((size_t)b * KCL + n) * CCH + chs * 32 + ch] = s * inv;
    if (t < 32) {  // n = 16
      float s2 = 0.f;
      #pragma unroll
      for (int w8 = 0; w8 < 8; ++w8) s2 += P[w8 * 1024 + 512 + t];
      out_sf[((size_t)b * KCL + 16) * CCH + chs * 32 + t] = s2 * inv;
    }
  }
}

extern "C" void kernel_launch(void* const* d_in, const int* in_sizes, int n_in,
                              void* d_out, int out_size, void* d_ws, size_t ws_size,
                              hipStream_t stream) {
  const float* x = (const float*)d_in[0];
  const float* w = (const float*)d_in[1];
  const float* bias = (const float*)d_in[2];
  float* out = (float*)d_out;
  float* outg = out;                 // (32,17)
  float* outsf = out + BATCH * KCL;  // (32,17,512)

  char* ws = (char*)d_ws;
  float* wT = (float*)(ws + WT_OFF);
  unsigned short* sig = (unsigned short*)(ws + SIG_OFF);
  unsigned short* xbf = (unsigned short*)(ws + XBF_OFF);

  k0_setup<<<1, 512, 0, stream>>>(w, wT, outg);

  const int k12_lds = 2 * KCL * 512 * 4;  // 69632
  hipFuncSetAttribute((const void*)k12_cam_sig,
                      hipFuncAttributeMaxDynamicSharedMemorySize, k12_lds);
  k12_cam_sig<<<BATCH * 8, 512, k12_lds, stream>>>(x, wT, bias, outg, xbf, sig);

  k3_sf<<<BATCH * 16, 512, 0, stream>>>(xbf, sig, outsf);
}

// Round 21
// 117.674 us; speedup vs baseline: 1.2559x; 1.1978x over previous
//
#include <hip/hip_runtime.h>
#include <cmath>

#define BATCH 32
#define CCH 512
#define HW 4096
#define KCL 17

typedef __attribute__((ext_vector_type(8))) short short8;
typedef __attribute__((ext_vector_type(16))) float f32x16;
typedef __attribute__((ext_vector_type(4))) float f32x4;

__device__ __forceinline__ unsigned pack_bf16(float a, float b) {
  unsigned ua = (__float_as_uint(a) + 0x8000u) >> 16;
  unsigned ub = (__float_as_uint(b) + 0x8000u) & 0xFFFF0000u;
  return ua | ub;
}
__device__ __forceinline__ f32x4 ntload4(const float* p) {
  return __builtin_nontemporal_load(reinterpret_cast<const f32x4*>(p));
}

// ws layout (bytes)
#define WT_OFF 0
#define WT_BYTES (CCH * 20 * 4)                    // 40960
#define SIG_OFF WT_BYTES
#define SIG_BYTES ((size_t)BATCH * 32 * HW * 2)    // 8388608   bf16 [b][32pad][4096]
#define XBF_OFF (SIG_OFF + SIG_BYTES)
#define XBF_BYTES ((size_t)BATCH * CCH * HW * 2)   // 134217728 bf16 [b][ch][4096]
#define WS_NEED (XBF_OFF + XBF_BYTES)              // ~143 MB (ws ~1 GB)

// K0: wT fill + zero out_g (g accumulated via atomics in k12)
__global__ void k0_setup(const float* __restrict__ w, float* __restrict__ wT,
                         float* __restrict__ out_g) {
  int c = threadIdx.x;  // 512
  #pragma unroll
  for (int k = 0; k < 20; ++k) wT[c * 20 + k] = (k < KCL) ? w[k * CCH + c] : 0.f;
  if (c < BATCH * KCL) out_g[c] = 0.f;
  if (c < BATCH * KCL - 512) out_g[512 + c] = 0.f;
}

// K12 (round-17 proven, 118 us): fused cam+sigmoid+xbf. Block = (b, 512-px
// slice), 512 thr: slab = readfirstlane(t>>7) (wave-uniform scalar w loads),
// 128 ch x 4 px per thread. Burst pipeline: group g+1 loads issue before
// group g FMA+xbf-stores; nt x-reads keep L3 free for xbf/sig (k3's inputs).
// Regular cached xbf stores (nt-stores regressed: r20).
__global__ __launch_bounds__(512)
void k12_cam_sig(const float* __restrict__ x, const float* __restrict__ wT,
                 const float* __restrict__ bias, float* __restrict__ out_g,
                 unsigned short* __restrict__ xbf, unsigned short* __restrict__ sig) {
  extern __shared__ float R[];  // [2][17][512] f32 = 69632 B
  const int t = threadIdx.x;
  const int slab = __builtin_amdgcn_readfirstlane(t >> 7);  // 0..3, wave-uniform
  const int pxg = t & 127;
  const int b = blockIdx.x >> 3;
  const int slice = blockIdx.x & 7;
  const int px = slice * 512 + pxg * 4;
  const float* xp = x + ((size_t)(b * CCH + slab * 128)) * HW + px;
  unsigned short* xbp = xbf + ((size_t)(b * CCH + slab * 128)) * HW + px;

  float cam[KCL][4];
  #pragma unroll
  for (int k = 0; k < KCL; ++k)
    #pragma unroll
    for (int i = 0; i < 4; ++i) cam[k][i] = 0.f;

  f32x4 v0[4], v1[4];
  #pragma unroll
  for (int j = 0; j < 4; ++j) v0[j] = ntload4(xp + (size_t)j * HW);

  #pragma unroll 1
  for (int gp = 0; gp < 16; ++gp) {
    const int c0 = gp * 8;
    #pragma unroll
    for (int j = 0; j < 4; ++j) v1[j] = ntload4(xp + (size_t)(c0 + 4 + j) * HW);
    #pragma unroll
    for (int j = 0; j < 4; ++j) {
      const f32x4 v = v0[j];
      const float* wr = wT + (slab * 128 + c0 + j) * 20;  // scalar (slab SGPR)
      #pragma unroll
      for (int k = 0; k < KCL; ++k) {
        cam[k][0] = fmaf(wr[k], v.x, cam[k][0]);
        cam[k][1] = fmaf(wr[k], v.y, cam[k][1]);
        cam[k][2] = fmaf(wr[k], v.z, cam[k][2]);
        cam[k][3] = fmaf(wr[k], v.w, cam[k][3]);
      }
      *reinterpret_cast<uint2*>(xbp + (size_t)(c0 + j) * HW) =
          make_uint2(pack_bf16(v.x, v.y), pack_bf16(v.z, v.w));
    }
    if (gp < 15) {
      #pragma unroll
      for (int j = 0; j < 4; ++j) v0[j] = ntload4(xp + (size_t)(c0 + 8 + j) * HW);
    }
    #pragma unroll
    for (int j = 0; j < 4; ++j) {
      const f32x4 v = v1[j];
      const float* wr = wT + (slab * 128 + c0 + 4 + j) * 20;
      #pragma unroll
      for (int k = 0; k < KCL; ++k) {
        cam[k][0] = fmaf(wr[k], v.x, cam[k][0]);
        cam[k][1] = fmaf(wr[k], v.y, cam[k][1]);
        cam[k][2] = fmaf(wr[k], v.z, cam[k][2]);
        cam[k][3] = fmaf(wr[k], v.w, cam[k][3]);
      }
      *reinterpret_cast<uint2*>(xbp + (size_t)(c0 + 4 + j) * HW) =
          make_uint2(pack_bf16(v.x, v.y), pack_bf16(v.z, v.w));
    }
  }

  // reduce 4 slab-partials -> slab 0
  if (slab >= 2) {
    float* Rb = R + (slab - 2) * (KCL * 512);
    #pragma unroll
    for (int k = 0; k < KCL; ++k)
      *reinterpret_cast<float4*>(Rb + k * 512 + pxg * 4) =
          make_float4(cam[k][0], cam[k][1], cam[k][2], cam[k][3]);
  }
  __syncthreads();
  if (slab < 2) {
    const float* Rb = R + slab * (KCL * 512);
    #pragma unroll
    for (int k = 0; k < KCL; ++k) {
      const float4 r = *reinterpret_cast<const float4*>(Rb + k * 512 + pxg * 4);
      cam[k][0] += r.x; cam[k][1] += r.y; cam[k][2] += r.z; cam[k][3] += r.w;
    }
  }
  __syncthreads();
  if (slab == 1) {
    #pragma unroll
    for (int k = 0; k < KCL; ++k)
      *reinterpret_cast<float4*>(R + k * 512 + pxg * 4) =
          make_float4(cam[k][0], cam[k][1], cam[k][2], cam[k][3]);
  }
  __syncthreads();
  if (slab == 0) {
    const float inv = 1.f / 4096.f;
    const int lane = t & 63;
    #pragma unroll
    for (int k = 0; k < KCL; ++k) {
      const float4 r = *reinterpret_cast<const float4*>(R + k * 512 + pxg * 4);
      const float bk = bias[k];
      float c0 = cam[k][0] + r.x + bk;
      float c1 = cam[k][1] + r.y + bk;
      float c2 = cam[k][2] + r.z + bk;
      float c3 = cam[k][3] + r.w + bk;
      unsigned u0 = pack_bf16(1.f / (1.f + __expf(-c0)), 1.f / (1.f + __expf(-c1)));
      unsigned u1 = pack_bf16(1.f / (1.f + __expf(-c2)), 1.f / (1.f + __expf(-c3)));
      *reinterpret_cast<uint2*>(sig + ((size_t)(b * 32 + k)) * HW + px) = make_uint2(u0, u1);
      float gk = c0 + c1 + c2 + c3;
      #pragma unroll
      for (int o = 1; o < 64; o <<= 1) gk += __shfl_xor(gk, o, 64);
      if (lane == 0) atomicAdd(out_g + b * KCL + k, gk * inv);
    }
  }
}

// K3: sf[b,:,chs*32..+32] = (1/4096) * xbf[32ch rows] @ sigT. Barrier-free MFMA
// global-gather from L3-resident xbf+sig; one sync for the 8-wave K-reduce.
__global__ __launch_bounds__(512, 2)
void k3_sf(const unsigned short* __restrict__ xbf, const unsigned short* __restrict__ sig,
           float* __restrict__ out_sf) {
  __shared__ float P[8 * 1024];  // 32 KB K-reduce scratch
  // XCD-chunked bijective swizzle: 512 blocks, 64 per XCD -> same-b blocks cluster
  const int p = blockIdx.x;
  const int lid = (p & 7) * 64 + (p >> 3);
  const int b = lid >> 4;
  const int chs = lid & 15;
  const int t = threadIdx.x;
  const int lane = t & 63;
  const int wv = __builtin_amdgcn_readfirstlane(t >> 6);  // 0..7, K-split
  const int m = lane & 31;
  const int h = lane >> 5;

  const unsigned short* ap = xbf + ((size_t)(b * CCH + chs * 32 + m)) * HW;
  const unsigned short* bp = sig + ((size_t)(b * 32 + m)) * HW;

  f32x16 acc;
  #pragma unroll
  for (int i = 0; i < 16; ++i) acc[i] = 0.f;

  // wave wv covers px slots [wv*64, wv*64+64): 2-KB contiguous stream per row
  const int obase = (wv * 64 + h) * 8;
  #pragma unroll 4
  for (int i = 0; i < 32; ++i) {
    const int o = obase + i * 16;  // ushort offset
    const short8 a = *reinterpret_cast<const short8*>(ap + o);
    const short8 bb = *reinterpret_cast<const short8*>(bp + o);
    acc = __builtin_amdgcn_mfma_f32_32x32x16_bf16(a, bb, acc, 0, 0, 0);
  }

  // K-reduce across 8 waves (validated C-layout map)
  #pragma unroll
  for (int r = 0; r < 16; ++r) {
    const int chr = (r & 3) + 8 * (r >> 2) + 4 * h;
    P[wv * 1024 + m * 32 + chr] = acc[r];  // index = cls*32 + ch
  }
  __syncthreads();
  const float inv = 1.f / 4096.f;
  {
    float s = 0.f;
    #pragma unroll
    for (int w8 = 0; w8 < 8; ++w8) s += P[w8 * 1024 + t];
    const int n = t >> 5, ch = t & 31;  // n = 0..15
    out_sf[((size_t)b * KCL + n) * CCH + chs * 32 + ch] = s * inv;
    if (t < 32) {  // n = 16
      float s2 = 0.f;
      #pragma unroll
      for (int w8 = 0; w8 < 8; ++w8) s2 += P[w8 * 1024 + 512 + t];
      out_sf[((size_t)b * KCL + 16) * CCH + chs * 32 + t] = s2 * inv;
    }
  }
}

extern "C" void kernel_launch(void* const* d_in, const int* in_sizes, int n_in,
                              void* d_out, int out_size, void* d_ws, size_t ws_size,
                              hipStream_t stream) {
  const float* x = (const float*)d_in[0];
  const float* w = (const float*)d_in[1];
  const float* bias = (const float*)d_in[2];
  float* out = (float*)d_out;
  float* outg = out;                 // (32,17)
  float* outsf = out + BATCH * KCL;  // (32,17,512)

  char* ws = (char*)d_ws;
  float* wT = (float*)(ws + WT_OFF);
  unsigned short* sig = (unsigned short*)(ws + SIG_OFF);
  unsigned short* xbf = (unsigned short*)(ws + XBF_OFF);

  k0_setup<<<1, 512, 0, stream>>>(w, wT, outg);

  const int k12_lds = 2 * KCL * 512 * 4;  // 69632
  hipFuncSetAttribute((const void*)k12_cam_sig,
                      hipFuncAttributeMaxDynamicSharedMemorySize, k12_lds);
  k12_cam_sig<<<BATCH * 8, 512, k12_lds, stream>>>(x, wT, bias, outg, xbf, sig);

  k3_sf<<<BATCH * 16, 512, 0, stream>>>(xbf, sig, outsf);
}